// Round 1
// baseline (137.899 us; speedup 1.0000x reference)
//
#include <hip/hip_runtime.h>
#include <stdint.h>

// BiaffineSpanHead: B=4, S=1024, IN=1024, H=256, C=8
// out[b,s,e,c] = sum_{h,g} Hs[b,s,h] U[h,c,g] He[b,e,g] + linS[b,s,c] + linE[b,e,c] + Wb[c]
//
// Pipeline (all bf16 MFMA, f32 accumulate):
//   cast seq_feats/start_w/end_w -> bf16 ; transpose+cast U -> Ut[(c,g)][h]
//   K1: Hs = X @ sw^T + sb  (M=4096,N=256,K=1024)  -> bf16   (x2 for He)
//   lin: linS[m,c], linE[m,c] (+bias)
//   K2: T[(b,s)][(c,g)] = Hs @ Ut^T  (M=4096,N=2048,K=256) -> bf16
//   K3: out = T[b] @ He[b]^T + lin epilogue (M=8192,N=1024,K=256, z=4)

#define BDIM 256

typedef float f32x4 __attribute__((ext_vector_type(4)));
typedef __bf16 bf16x8 __attribute__((ext_vector_type(8)));
typedef unsigned int u32;
typedef const __attribute__((address_space(1))) u32* gas_ptr;
typedef __attribute__((address_space(3))) u32* las_ptr;

static __device__ __forceinline__ void load_lds16(const void* g, void* l) {
  __builtin_amdgcn_global_load_lds((gas_ptr)g, (las_ptr)l, 16, 0, 0);
}

static __device__ __forceinline__ unsigned short f32_to_bf16(float f) {
  union { float f; u32 u; } v; v.f = f;
  u32 r = v.u + 0x7FFFu + ((v.u >> 16) & 1u);
  return (unsigned short)(r >> 16);
}
static __device__ __forceinline__ float bf16lo_to_f32(u32 u) {
  union { u32 u; float f; } v; v.u = u << 16;
  return v.f;
}
static __device__ __forceinline__ float bf16hi_to_f32(u32 u) {
  union { u32 u; float f; } v; v.u = u & 0xFFFF0000u;
  return v.f;
}

// ---------------------------------------------------------------------------
// Generic B^T GEMM: Out[m,n] = sum_k A[m,k] * B[n,k], A: MxK bf16, B: NxK bf16
// 128x128 tile, BK=32, 256 threads (4 waves, 2x2), 16x16x32 bf16 MFMA.
// EPI: 0 = bf16 out, 1 = bf16 out + bias[n], 2 = biaff f32 out + lin epilogue
// ---------------------------------------------------------------------------
template <int EPI>
__global__ __launch_bounds__(BDIM, 2)
void gemm_bt(const unsigned short* __restrict__ Aall,
             const unsigned short* __restrict__ Ball,
             void* __restrict__ OutAll,
             const int M, const int N, const int K,
             const long long strideA, const long long strideB, const long long strideO,
             const float* __restrict__ bias,
             const float* __restrict__ linSall,
             const float* __restrict__ linEall)
{
  __shared__ unsigned short lsA[128 * 32];
  __shared__ unsigned short lsB[128 * 32];

  const int tid  = threadIdx.x;
  const int lane = tid & 63;
  const int wv   = tid >> 6;
  const int wr   = wv >> 1;   // wave row (0..1), 64 rows each
  const int wc   = wv & 1;    // wave col (0..1), 64 cols each
  const int z    = blockIdx.z;
  const int n0   = blockIdx.x * 128;
  const int m0   = blockIdx.y * 128;

  const unsigned short* A  = Aall + (size_t)z * strideA;
  const unsigned short* Bm = Ball + (size_t)z * strideB;

  f32x4 acc[4][4];
#pragma unroll
  for (int i = 0; i < 4; ++i)
#pragma unroll
    for (int j = 0; j < 4; ++j) acc[i][j] = (f32x4)0.f;

  const int rA = lane & 15;        // fragment row (A) / col (B)
  const int ko = (lane >> 4) * 8;  // k offset within BK=32

  for (int kt = 0; kt < K; kt += 32) {
    // stage A,B tiles: 128 rows x 32 k x 2B = 8KB each = 512 x 16B chunks
#pragma unroll
    for (int it = 0; it < 2; ++it) {
      const int chunk = it * BDIM + tid;
      const int row = chunk >> 2;
      const int ce = (chunk & 3) * 8;
      load_lds16(A  + (size_t)(m0 + row) * K + (kt + ce), &lsA[chunk * 8]);
      load_lds16(Bm + (size_t)(n0 + row) * K + (kt + ce), &lsB[chunk * 8]);
    }
    __syncthreads();

    bf16x8 aF[4], bF[4];
#pragma unroll
    for (int i = 0; i < 4; ++i)
      aF[i] = *reinterpret_cast<const bf16x8*>(&lsA[(wr * 64 + i * 16 + rA) * 32 + ko]);
#pragma unroll
    for (int j = 0; j < 4; ++j)
      bF[j] = *reinterpret_cast<const bf16x8*>(&lsB[(wc * 64 + j * 16 + rA) * 32 + ko]);
#pragma unroll
    for (int i = 0; i < 4; ++i)
#pragma unroll
      for (int j = 0; j < 4; ++j)
        acc[i][j] = __builtin_amdgcn_mfma_f32_16x16x32_bf16(aF[i], bF[j], acc[i][j], 0, 0, 0);
    __syncthreads();
  }

  // C/D layout: col = lane&15, row = (lane>>4)*4 + reg   [m89 verified]
  const int rgr = (lane >> 4) * 4;

  if constexpr (EPI == 2) {
    float* Out = (float*)OutAll + (size_t)z * strideO;
    const float* lS = linSall + (size_t)z * 8192;
    const float* lE = linEall + (size_t)z * 8192;
#pragma unroll
    for (int i = 0; i < 4; ++i) {
#pragma unroll
      for (int j = 0; j < 4; ++j) {
        const int mBase = m0 + wr * 64 + i * 16 + rgr;
        const int e = n0 + wc * 64 + j * 16 + rA;
#pragma unroll
        for (int r = 0; r < 4; ++r) {
          const int m = mBase + r;        // m = s*8 + c
          const int s = m >> 3;
          const int c = m & 7;
          Out[((size_t)s << 13) + ((size_t)e << 3) + c] =
              acc[i][j][r] + lS[m] + lE[(e << 3) + c];
        }
      }
    }
  } else {
    unsigned short* Out = (unsigned short*)OutAll;
#pragma unroll
    for (int i = 0; i < 4; ++i) {
#pragma unroll
      for (int j = 0; j < 4; ++j) {
        const int mBase = m0 + wr * 64 + i * 16 + rgr;
        const int n = n0 + wc * 64 + j * 16 + rA;
        const float bn = (EPI == 1) ? bias[n] : 0.f;
#pragma unroll
        for (int r = 0; r < 4; ++r) {
          Out[(size_t)(mBase + r) * N + n] = f32_to_bf16(acc[i][j][r] + bn);
        }
      }
    }
  }
}

// ---------------------------------------------------------------------------
__global__ void cast_f32_bf16(const float* __restrict__ src,
                              unsigned short* __restrict__ dst, const int n)
{
  const int i = (blockIdx.x * BDIM + threadIdx.x) * 4;
  if (i >= n) return;
  const float4 v = *reinterpret_cast<const float4*>(src + i);
  ushort4 o;
  o.x = f32_to_bf16(v.x);
  o.y = f32_to_bf16(v.y);
  o.z = f32_to_bf16(v.z);
  o.w = f32_to_bf16(v.w);
  *reinterpret_cast<ushort4*>(dst + i) = o;
}

// U (256, 8, 256) f32 -> Ut[(c,g)][h] bf16 (2048 x 256)
__global__ void u_transpose(const float* __restrict__ U, unsigned short* __restrict__ Ut)
{
  const int idx = blockIdx.x * BDIM + threadIdx.x; // n*256 + h
  if (idx >= 2048 * 256) return;
  const int h = idx & 255;
  const int n = idx >> 8;
  Ut[idx] = f32_to_bf16(U[(size_t)h * 2048 + n]);
}

// linS[m,c] = Hs[m,:].Ws[c,:] ; linE[m,c] = He[m,:].We[c,:] + Wb[c]
__global__ void lin_kernel(const unsigned short* __restrict__ Hs,
                           const unsigned short* __restrict__ He,
                           const float* __restrict__ Ww,
                           const float* __restrict__ Wb,
                           float* __restrict__ linS,
                           float* __restrict__ linE)
{
  const int idx = blockIdx.x * BDIM + threadIdx.x; // (m,c), m in [0,4096)
  if (idx >= 4096 * 8) return;
  const int m = idx >> 3;
  const int c = idx & 7;
  const uint4* hs4 = reinterpret_cast<const uint4*>(Hs + (size_t)m * 256);
  const uint4* he4 = reinterpret_cast<const uint4*>(He + (size_t)m * 256);
  const float* ws = Ww + c * 512;
  const float* we = ws + 256;
  float s1 = 0.f, s2 = 0.f;
#pragma unroll 4
  for (int t = 0; t < 32; ++t) {
    const uint4 a = hs4[t];
    const uint4 b = he4[t];
    const u32 aw[4] = {a.x, a.y, a.z, a.w};
    const u32 bw[4] = {b.x, b.y, b.z, b.w};
#pragma unroll
    for (int q = 0; q < 4; ++q) {
      const int h = t * 8 + q * 2;
      s1 += bf16lo_to_f32(aw[q]) * ws[h] + bf16hi_to_f32(aw[q]) * ws[h + 1];
      s2 += bf16lo_to_f32(bw[q]) * we[h] + bf16hi_to_f32(bw[q]) * we[h + 1];
    }
  }
  linS[idx] = s1;
  linE[idx] = s2 + Wb[c];
}

// ---------------------------------------------------------------------------
extern "C" void kernel_launch(void* const* d_in, const int* in_sizes, int n_in,
                              void* d_out, int out_size, void* d_ws, size_t ws_size,
                              hipStream_t stream)
{
  const float* seq = (const float*)d_in[0];   // (4,1024,1024)
  const float* U   = (const float*)d_in[1];   // (256,8,256)
  const float* Ww  = (const float*)d_in[2];   // (8,512)
  const float* Wb  = (const float*)d_in[3];   // (8)
  const float* sw  = (const float*)d_in[4];   // (256,1024)
  const float* sb  = (const float*)d_in[5];   // (256)
  const float* ew  = (const float*)d_in[6];   // (256,1024)
  const float* eb  = (const float*)d_in[7];   // (256)
  float* out = (float*)d_out;                 // (4,1024,1024,8)

  // workspace layout (bytes): ~30.3 MiB total
  unsigned short* Xbf  = (unsigned short*)d_ws;      // 4194304 elems
  unsigned short* swbf = Xbf  + 4194304;             // 262144
  unsigned short* ewbf = swbf + 262144;              // 262144
  unsigned short* Utbf = ewbf + 262144;              // 524288
  unsigned short* Hsbf = Utbf + 524288;              // 1048576
  unsigned short* Hebf = Hsbf + 1048576;             // 1048576
  unsigned short* Tbf  = Hebf + 1048576;             // 8388608
  float* linS = (float*)(Tbf + 8388608);             // 32768 floats
  float* linE = linS + 32768;                        // 32768 floats

  // casts
  cast_f32_bf16<<<4096, BDIM, 0, stream>>>(seq, Xbf, 4194304);
  cast_f32_bf16<<<256,  BDIM, 0, stream>>>(sw, swbf, 262144);
  cast_f32_bf16<<<256,  BDIM, 0, stream>>>(ew, ewbf, 262144);
  u_transpose<<<2048, BDIM, 0, stream>>>(U, Utbf);

  // K1: Hs/He = X @ w^T + b   (M=4096, N=256, K=1024)
  gemm_bt<1><<<dim3(2, 32, 1), BDIM, 0, stream>>>(
      Xbf, swbf, Hsbf, 4096, 256, 1024, 0, 0, 0, sb, nullptr, nullptr);
  gemm_bt<1><<<dim3(2, 32, 1), BDIM, 0, stream>>>(
      Xbf, ewbf, Hebf, 4096, 256, 1024, 0, 0, 0, eb, nullptr, nullptr);

  // lin terms
  lin_kernel<<<128, BDIM, 0, stream>>>(Hsbf, Hebf, Ww, Wb, linS, linE);

  // K2: T = Hs @ Ut^T   (M=4096, N=2048, K=256)
  gemm_bt<0><<<dim3(16, 32, 1), BDIM, 0, stream>>>(
      Hsbf, Utbf, Tbf, 4096, 2048, 256, 0, 0, 0, nullptr, nullptr, nullptr);

  // K3: out[b] = T[b] @ He[b]^T + lin   (M=8192, N=1024, K=256, z=4)
  gemm_bt<2><<<dim3(8, 64, 4), BDIM, 0, stream>>>(
      Tbf, Hebf, out, 8192, 1024, 256,
      (long long)8192 * 256, (long long)1024 * 256, (long long)8388608,
      nullptr, linS, linE);
}

// Round 2
// 98.472 us; speedup vs baseline: 1.4004x; 1.4004x over previous
//
#include <hip/hip_runtime.h>
#include <stdint.h>

// BiaffineSpanHead: B=4, S=1024, IN=1024, H=256, C=8
// out[b,s,e,c] = sum_{h,g} Hs[b,s,h] U[h,c,g] He[b,e,g] + linS[b,s,c] + linE[b,e,c] + Wb[c]
//
// R2: fused prep (1 kernel), fused Hs+He GEMM (N=512, 64x128 tile, 256 blocks),
//     float4 epilogue on K3, XCD swizzle, 5 launches total.

#define BDIM 256

typedef float f32x4 __attribute__((ext_vector_type(4)));
typedef __bf16 bf16x8 __attribute__((ext_vector_type(8)));
typedef unsigned int u32;
typedef const __attribute__((address_space(1))) u32* gas_ptr;
typedef __attribute__((address_space(3))) u32* las_ptr;

static __device__ __forceinline__ void load_lds16(const void* g, void* l) {
  __builtin_amdgcn_global_load_lds((gas_ptr)g, (las_ptr)l, 16, 0, 0);
}

static __device__ __forceinline__ unsigned short f32_to_bf16(float f) {
  union { float f; u32 u; } v; v.f = f;
  u32 r = v.u + 0x7FFFu + ((v.u >> 16) & 1u);
  return (unsigned short)(r >> 16);
}
static __device__ __forceinline__ float bf16lo_to_f32(u32 u) {
  union { u32 u; float f; } v; v.u = u << 16;
  return v.f;
}
static __device__ __forceinline__ float bf16hi_to_f32(u32 u) {
  union { u32 u; float f; } v; v.u = u & 0xFFFF0000u;
  return v.f;
}

// ---------------------------------------------------------------------------
// B^T GEMM: Out[m,n] = sum_k A[m,k]*B[n,k].  Tile (IM*32) x 128, BK=32,
// 256 threads (4 waves 2x2), 16x16x32 bf16 MFMA.
// EPI: 0 = bf16 out; 1 = bf16 out + dual bias (n<256 ? b0[n] : b1[n-256]);
//      2 = f32 biaff out + lin epilogue (float4 stores)
// ---------------------------------------------------------------------------
template <int IM, int EPI>
__global__ __launch_bounds__(BDIM, 2)
void gemm_bt(const unsigned short* __restrict__ Aall,
             const unsigned short* __restrict__ Ball,
             void* __restrict__ OutAll,
             const int N, const int K, const int lda, const int ldb,
             const long long strideA, const long long strideB, const long long strideO,
             const float* __restrict__ bias0,
             const float* __restrict__ bias1,
             const float* __restrict__ linSall,
             const float* __restrict__ linEall)
{
  constexpr int WM = IM * 16;   // rows per wave-tile
  constexpr int TM = 2 * WM;    // block tile M

  __shared__ unsigned short lsA[TM * 32];
  __shared__ unsigned short lsB[128 * 32];

  const int tid  = threadIdx.x;
  const int lane = tid & 63;
  const int wv   = tid >> 6;
  const int wr   = wv >> 1;
  const int wc   = wv & 1;
  const int z    = blockIdx.z;

  // XCD-aware bijective swizzle over the (x,y) grid (nwg % 8 == 0 always here)
  const int gx = gridDim.x;
  const int nwg = gx * gridDim.y;
  int id = blockIdx.y * gx + blockIdx.x;
  {
    const int q = nwg >> 3;
    id = (id & 7) * q + (id >> 3);
  }
  const int n0 = (id % gx) * 128;
  const int m0 = (id / gx) * TM;

  const unsigned short* A  = Aall + (size_t)z * strideA;
  const unsigned short* Bm = Ball + (size_t)z * strideB;

  f32x4 acc[IM][4];
#pragma unroll
  for (int i = 0; i < IM; ++i)
#pragma unroll
    for (int j = 0; j < 4; ++j) acc[i][j] = (f32x4)0.f;

  const int rA = lane & 15;        // fragment row (A) / col (B)
  const int ko = (lane >> 4) * 8;  // k offset within BK=32

  for (int kt = 0; kt < K; kt += 32) {
    constexpr int CA = TM * 4;     // 16B chunks for A tile
#pragma unroll
    for (int it = 0; it < CA / BDIM; ++it) {
      const int chunk = it * BDIM + tid;
      const int row = chunk >> 2;
      const int ce = (chunk & 3) * 8;
      load_lds16(A + (size_t)(m0 + row) * lda + (kt + ce), &lsA[chunk * 8]);
    }
#pragma unroll
    for (int it = 0; it < 2; ++it) {
      const int chunk = it * BDIM + tid;
      const int row = chunk >> 2;
      const int ce = (chunk & 3) * 8;
      load_lds16(Bm + (size_t)(n0 + row) * ldb + (kt + ce), &lsB[chunk * 8]);
    }
    __syncthreads();

    bf16x8 aF[IM], bF[4];
#pragma unroll
    for (int i = 0; i < IM; ++i)
      aF[i] = *reinterpret_cast<const bf16x8*>(&lsA[(wr * WM + i * 16 + rA) * 32 + ko]);
#pragma unroll
    for (int j = 0; j < 4; ++j)
      bF[j] = *reinterpret_cast<const bf16x8*>(&lsB[(wc * 64 + j * 16 + rA) * 32 + ko]);
#pragma unroll
    for (int i = 0; i < IM; ++i)
#pragma unroll
      for (int j = 0; j < 4; ++j)
        acc[i][j] = __builtin_amdgcn_mfma_f32_16x16x32_bf16(aF[i], bF[j], acc[i][j], 0, 0, 0);
    __syncthreads();
  }

  // C/D layout: col = lane&15, row = (lane>>4)*4 + reg   [m89 verified]
  const int rgr = (lane >> 4) * 4;

  if constexpr (EPI == 2) {
    float* Out = (float*)OutAll + (size_t)z * strideO;
    const float* lS = linSall + (size_t)z * 8192;
    const float* lE = linEall + (size_t)z * 8192;
#pragma unroll
    for (int i = 0; i < IM; ++i) {
#pragma unroll
      for (int j = 0; j < 4; ++j) {
        const int mBase = m0 + wr * WM + i * 16 + rgr;   // = s*8 + c0, c0 in {0,4}
        const int e = n0 + wc * 64 + j * 16 + rA;
        const int s = mBase >> 3;
        const int c0 = mBase & 7;
        const float4 ls4 = *reinterpret_cast<const float4*>(lS + mBase);
        const float4 le4 = *reinterpret_cast<const float4*>(lE + (e << 3) + c0);
        float4 o;
        o.x = acc[i][j][0] + ls4.x + le4.x;
        o.y = acc[i][j][1] + ls4.y + le4.y;
        o.z = acc[i][j][2] + ls4.z + le4.z;
        o.w = acc[i][j][3] + ls4.w + le4.w;
        *reinterpret_cast<float4*>(Out + ((size_t)s << 13) + ((size_t)e << 3) + c0) = o;
      }
    }
  } else {
    unsigned short* Out = (unsigned short*)OutAll;
#pragma unroll
    for (int i = 0; i < IM; ++i) {
#pragma unroll
      for (int j = 0; j < 4; ++j) {
        const int mBase = m0 + wr * WM + i * 16 + rgr;
        const int n = n0 + wc * 64 + j * 16 + rA;
        float bn = 0.f;
        if constexpr (EPI == 1) bn = (n < 256) ? bias0[n] : bias1[n - 256];
#pragma unroll
        for (int r = 0; r < 4; ++r) {
          Out[(size_t)(mBase + r) * N + n] = f32_to_bf16(acc[i][j][r] + bn);
        }
      }
    }
  }
}

// ---------------------------------------------------------------------------
// Fused prep: seq cast (blocks 0..4095), weight concat-cast (4096..4607),
// U transpose+cast (4608..5119). 1024 elems per block.
__global__ void prep_kernel(const float* __restrict__ seq,
                            const float* __restrict__ sw,
                            const float* __restrict__ ew,
                            const float* __restrict__ U,
                            unsigned short* __restrict__ Xbf,
                            unsigned short* __restrict__ wbf,
                            unsigned short* __restrict__ Ut)
{
  const int bid = blockIdx.x;
  const int tid = threadIdx.x;
  if (bid < 4096) {
    const int i = bid * 1024 + tid * 4;
    const float4 v = *reinterpret_cast<const float4*>(seq + i);
    ushort4 o;
    o.x = f32_to_bf16(v.x); o.y = f32_to_bf16(v.y);
    o.z = f32_to_bf16(v.z); o.w = f32_to_bf16(v.w);
    *reinterpret_cast<ushort4*>(Xbf + i) = o;
  } else if (bid < 4608) {
    const int i = (bid - 4096) * 1024 + tid * 4;
    const float* src = (i < 262144) ? (sw + i) : (ew + (i - 262144));
    const float4 v = *reinterpret_cast<const float4*>(src);
    ushort4 o;
    o.x = f32_to_bf16(v.x); o.y = f32_to_bf16(v.y);
    o.z = f32_to_bf16(v.z); o.w = f32_to_bf16(v.w);
    *reinterpret_cast<ushort4*>(wbf + i) = o;
  } else {
    const int i = (bid - 4608) * 1024 + tid * 4;  // i = n*256 + h
    const int n = i >> 8;
    const int h = i & 255;
    ushort4 o;
    o.x = f32_to_bf16(U[(size_t)(h + 0) * 2048 + n]);
    o.y = f32_to_bf16(U[(size_t)(h + 1) * 2048 + n]);
    o.z = f32_to_bf16(U[(size_t)(h + 2) * 2048 + n]);
    o.w = f32_to_bf16(U[(size_t)(h + 3) * 2048 + n]);
    *reinterpret_cast<ushort4*>(Ut + i) = o;
  }
}

// linS[m,c] = Hs[m,:].Ws[c,:] ; linE[m,c] = He[m,:].We[c,:] + Wb[c]
// Hboth is [4096][512]: cols 0..255 = Hs, 256..511 = He
__global__ void lin_kernel(const unsigned short* __restrict__ Hboth,
                           const float* __restrict__ Ww,
                           const float* __restrict__ Wb,
                           float* __restrict__ linS,
                           float* __restrict__ linE)
{
  const int idx = blockIdx.x * BDIM + threadIdx.x; // (m,c), m in [0,4096)
  if (idx >= 4096 * 8) return;
  const int m = idx >> 3;
  const int c = idx & 7;
  const uint4* hs4 = reinterpret_cast<const uint4*>(Hboth + (size_t)m * 512);
  const uint4* he4 = reinterpret_cast<const uint4*>(Hboth + (size_t)m * 512 + 256);
  const float* ws = Ww + c * 512;
  const float* we = ws + 256;
  float s1 = 0.f, s2 = 0.f;
#pragma unroll 4
  for (int t = 0; t < 32; ++t) {
    const uint4 a = hs4[t];
    const uint4 b = he4[t];
    const u32 aw[4] = {a.x, a.y, a.z, a.w};
    const u32 bw[4] = {b.x, b.y, b.z, b.w};
#pragma unroll
    for (int q = 0; q < 4; ++q) {
      const int h = t * 8 + q * 2;
      s1 += bf16lo_to_f32(aw[q]) * ws[h] + bf16hi_to_f32(aw[q]) * ws[h + 1];
      s2 += bf16lo_to_f32(bw[q]) * we[h] + bf16hi_to_f32(bw[q]) * we[h + 1];
    }
  }
  linS[idx] = s1;
  linE[idx] = s2 + Wb[c];
}

// ---------------------------------------------------------------------------
extern "C" void kernel_launch(void* const* d_in, const int* in_sizes, int n_in,
                              void* d_out, int out_size, void* d_ws, size_t ws_size,
                              hipStream_t stream)
{
  const float* seq = (const float*)d_in[0];   // (4,1024,1024)
  const float* U   = (const float*)d_in[1];   // (256,8,256)
  const float* Ww  = (const float*)d_in[2];   // (8,512)
  const float* Wb  = (const float*)d_in[3];   // (8)
  const float* sw  = (const float*)d_in[4];   // (256,1024)
  const float* sb  = (const float*)d_in[5];   // (256)
  const float* ew  = (const float*)d_in[6];   // (256,1024)
  const float* eb  = (const float*)d_in[7];   // (256)
  float* out = (float*)d_out;                 // (4,1024,1024,8)

  // workspace layout (ushort units; total ~31.7 MB)
  unsigned short* Xbf   = (unsigned short*)d_ws;       // 4194304
  unsigned short* wbf   = Xbf  + 4194304;              // 524288  [512][1024]
  unsigned short* Utbf  = wbf  + 524288;               // 524288  [2048][256]
  unsigned short* Hboth = Utbf + 524288;               // 2097152 [4096][512]
  unsigned short* Tbf   = Hboth + 2097152;             // 8388608 [4096][2048]
  float* linS = (float*)(Tbf + 8388608);               // 32768
  float* linE = linS + 32768;                          // 32768

  // prep: all casts + U transpose in one kernel
  prep_kernel<<<5120, BDIM, 0, stream>>>(seq, sw, ew, U, Xbf, wbf, Utbf);

  // K1: Hboth = X @ [sw;ew]^T + [sb;eb]  (M=4096, N=512, K=1024), 64x128 tile
  gemm_bt<2, 1><<<dim3(4, 64, 1), BDIM, 0, stream>>>(
      Xbf, wbf, Hboth, 512, 1024, 1024, 1024, 0, 0, 0, sb, eb, nullptr, nullptr);

  // lin terms
  lin_kernel<<<128, BDIM, 0, stream>>>(Hboth, Ww, Wb, linS, linE);

  // K2: T = Hs @ Ut^T   (M=4096, N=2048, K=256), 128x128 tile
  gemm_bt<4, 0><<<dim3(16, 32, 1), BDIM, 0, stream>>>(
      Hboth, Utbf, Tbf, 2048, 256, 512, 256, 0, 0, 0,
      nullptr, nullptr, nullptr, nullptr);

  // K3: out[b] = T[b] @ He[b]^T + lin   (M=8192, N=1024, K=256, z=4)
  gemm_bt<4, 2><<<dim3(8, 64, 4), BDIM, 0, stream>>>(
      Tbf, Hboth + 256, out, 1024, 256, 256, 512,
      (long long)8192 * 256, (long long)1024 * 512, (long long)8388608,
      nullptr, nullptr, linS, linE);
}

// Round 4
// 97.330 us; speedup vs baseline: 1.4168x; 1.0117x over previous
//
#include <hip/hip_runtime.h>
#include <stdint.h>

// BiaffineSpanHead: B=4, S=1024, IN=1024, H=256, C=8
// out[b,s,e,c] = sum_{h,g} Hs[b,s,h] U[h,c,g] He[b,e,g] + linS[b,s,c] + linE[b,e,c] + Wb[c]
//
// R4 = R3 with the missing batch offset on K3's B operand fixed (Bgz).

#define BDIM 256

typedef float f32x4 __attribute__((ext_vector_type(4)));
typedef __bf16 bf16x8 __attribute__((ext_vector_type(8)));
typedef unsigned int u32;
typedef unsigned short u16;
typedef const __attribute__((address_space(1))) u32* gas_ptr;
typedef __attribute__((address_space(3))) u32* las_ptr;

static __device__ __forceinline__ void load_lds16(const void* g, void* l) {
  __builtin_amdgcn_global_load_lds((gas_ptr)g, (las_ptr)l, 16, 0, 0);
}

static __device__ __forceinline__ u16 f32_to_bf16(float f) {
  union { float f; u32 u; } v; v.f = f;
  u32 r = v.u + 0x7FFFu + ((v.u >> 16) & 1u);
  return (u16)(r >> 16);
}
static __device__ __forceinline__ float bf16lo_to_f32(u32 u) {
  union { u32 u; float f; } v; v.u = u << 16;
  return v.f;
}
static __device__ __forceinline__ float bf16hi_to_f32(u32 u) {
  union { u32 u; float f; } v; v.u = u & 0xFFFF0000u;
  return v.f;
}

// ---------------------------------------------------------------------------
// K3: 256x256 tile, BK=64, 512 threads (8 waves, 2M x 4N), 8-phase pipeline.
// A = T[z] as [8192][256] bf16 (lda=256); B = He[z] rows (ldb=512).
// Out[z][s][e][c] f32 with lin epilogue.
// LDS: 2 bufs x (A[256][64] + B[256][64]) bf16 = 128 KB (dynamic).
// Swizzle: LDS slot j of row r holds global k-group j ^ (r&7); staged via
// pre-swizzled global source (rule #21), read with the same XOR.
// ---------------------------------------------------------------------------
#define K3_LDSA(b) ((b) * 32768)
#define K3_LDSB(b) ((b) * 32768 + 16384)

#define STG(dstofs, src, srow, ld, kt)                                         \
  load_lds16((src) + (size_t)((srow) + (tid >> 3)) * (ld) + (kt) +             \
                 (((tid & 7) ^ ((tid >> 3) & 7)) << 3),                        \
             &lds[(dstofs) + tid * 8])

#define STG_A(b, mh, t) do {                                                   \
    STG(K3_LDSA(b) + (mh) * 4096,       Ag, m0 + (mh) * 64,       256, (t)*64);\
    STG(K3_LDSA(b) + ((mh)+2) * 4096,   Ag, m0 + 128 + (mh) * 64, 256, (t)*64);\
  } while (0)

#define STG_B(b, h, t) do {                                                    \
    STG(K3_LDSB(b) + (2*(h)) * 4096,    Bgz, n0 + (h) * 128,      512, (t)*64);\
    STG(K3_LDSB(b) + (2*(h)+1) * 4096,  Bgz, n0 + (h) * 128 + 64, 512, (t)*64);\
  } while (0)

#define RD_A(b, mh)                                                            \
  _Pragma("unroll")                                                            \
  for (int mi = 0; mi < 4; ++mi) {                                             \
    const int r = wr * 128 + (mh) * 64 + mi * 16 + rA;                         \
    _Pragma("unroll")                                                          \
    for (int ks = 0; ks < 2; ++ks)                                             \
      aF[mi][ks] = *reinterpret_cast<const bf16x8*>(                           \
          &lds[K3_LDSA(b) + r * 64 + ((((ks << 2) | kq) ^ (rA & 7)) << 3)]);   \
  }

#define RD_B(b)                                                                \
  _Pragma("unroll")                                                            \
  for (int nh = 0; nh < 2; ++nh)                                               \
  _Pragma("unroll")                                                            \
  for (int ni = 0; ni < 2; ++ni) {                                             \
    const int r = wc * 64 + nh * 32 + ni * 16 + rA;                            \
    _Pragma("unroll")                                                          \
    for (int ks = 0; ks < 2; ++ks)                                             \
      bF[nh][ni][ks] = *reinterpret_cast<const bf16x8*>(                       \
          &lds[K3_LDSB(b) + r * 64 + ((((ks << 2) | kq) ^ (rA & 7)) << 3)]);   \
  }

#define MFMA_Q(mh, nh)                                                         \
  __builtin_amdgcn_s_setprio(1);                                               \
  _Pragma("unroll")                                                            \
  for (int mi = 0; mi < 4; ++mi)                                               \
  _Pragma("unroll")                                                            \
  for (int ni = 0; ni < 2; ++ni)                                               \
  _Pragma("unroll")                                                            \
  for (int ks = 0; ks < 2; ++ks)                                               \
    acc[(mh)*4 + mi][(nh)*2 + ni] = __builtin_amdgcn_mfma_f32_16x16x32_bf16(   \
        aF[mi][ks], bF[nh][ni][ks], acc[(mh)*4 + mi][(nh)*2 + ni], 0, 0, 0);   \
  __builtin_amdgcn_s_setprio(0);

#define BARRIER_MID()                                                          \
  __builtin_amdgcn_sched_barrier(0);                                           \
  __builtin_amdgcn_s_barrier();                                                \
  asm volatile("s_waitcnt lgkmcnt(0)" ::: "memory");                           \
  __builtin_amdgcn_sched_barrier(0)

#define BARRIER_END()                                                          \
  __builtin_amdgcn_sched_barrier(0);                                           \
  __builtin_amdgcn_s_barrier()

__global__ __launch_bounds__(512, 2)
void gemm256_biaff(const u16* __restrict__ Tall,   // [z][8192][256]
                   const u16* __restrict__ Bg,     // He = Hboth+256, ldb=512
                   float* __restrict__ Out,        // [z][1024][1024][8]
                   const float* __restrict__ linSall,
                   const float* __restrict__ linEall)
{
  extern __shared__ u16 lds[];

  const int tid  = threadIdx.x;        // 0..511
  const int lane = tid & 63;
  const int wv   = tid >> 6;           // 0..7
  const int wr   = wv >> 2;            // 0..1
  const int wc   = wv & 3;             // 0..3
  const int rA   = lane & 15;
  const int kq   = lane >> 4;          // 0..3
  const int z    = blockIdx.z;

  // XCD-aware bijective swizzle (nwg = 128, q = 16)
  int id = blockIdx.y * gridDim.x + blockIdx.x;
  id = (id & 7) * 16 + (id >> 3);
  const int n0 = (id & 3) * 256;
  const int m0 = (id >> 2) * 256;

  const u16* Ag  = Tall + (size_t)z * (8192 * 256);
  const u16* Bgz = Bg   + (size_t)z * (1024 * 512);   // <-- R4 fix

  f32x4 acc[8][4];
#pragma unroll
  for (int i = 0; i < 8; ++i)
#pragma unroll
    for (int j = 0; j < 4; ++j) acc[i][j] = (f32x4)0.f;

  bf16x8 aF[4][2];
  bf16x8 bF[2][2][2];

  // ---- prologue: tile0 -> buf0 (full), tile1.A-mh0 -> buf1
  STG_A(0, 0, 0); STG_A(0, 1, 0); STG_B(0, 0, 0); STG_B(0, 1, 0);
  STG_A(1, 0, 1);
  asm volatile("s_waitcnt vmcnt(2)" ::: "memory");
  __builtin_amdgcn_s_barrier();

  constexpr int NT = 4;  // K=256 / BK=64
#pragma unroll
  for (int i = 0; i < NT / 2; ++i) {
    const int t1 = 2 * i + 1, t2 = 2 * i + 2, t3 = 2 * i + 3;
    // ph1: MFMA buf0 quad(0,0)
    RD_A(0, 0); RD_B(0);
    STG_A(1, 1, t1);
    BARRIER_MID();
    MFMA_Q(0, 0);
    BARRIER_END();
    // ph2: quad(0,1)
    STG_B(1, 0, t1);
    BARRIER_MID();
    MFMA_Q(0, 1);
    BARRIER_END();
    // ph3: quad(1,1)
    RD_A(0, 1);
    STG_B(1, 1, t1);
    BARRIER_MID();
    MFMA_Q(1, 1);
    BARRIER_END();
    // ph4: quad(1,0); buf1 tile t1 must be landed after this vmcnt
    if (t2 < NT) {
      STG_A(0, 0, t2);
      asm volatile("s_waitcnt vmcnt(2)" ::: "memory");
    } else {
      asm volatile("s_waitcnt vmcnt(0)" ::: "memory");
    }
    BARRIER_MID();
    MFMA_Q(1, 0);
    BARRIER_END();
    // ph5: MFMA buf1 quad(0,0)
    RD_A(1, 0); RD_B(1);
    if (t2 < NT) STG_A(0, 1, t2);
    BARRIER_MID();
    MFMA_Q(0, 0);
    BARRIER_END();
    // ph6: quad(0,1)
    if (t2 < NT) STG_B(0, 0, t2);
    BARRIER_MID();
    MFMA_Q(0, 1);
    BARRIER_END();
    // ph7: quad(1,1)
    RD_A(1, 1);
    if (t2 < NT) STG_B(0, 1, t2);
    BARRIER_MID();
    MFMA_Q(1, 1);
    BARRIER_END();
    // ph8: quad(1,0); buf0 tile t2 must be landed after this vmcnt
    if (t3 < NT) {
      STG_A(1, 0, t3);
      asm volatile("s_waitcnt vmcnt(2)" ::: "memory");
    } else {
      asm volatile("s_waitcnt vmcnt(0)" ::: "memory");
    }
    BARRIER_MID();
    MFMA_Q(1, 0);
    BARRIER_END();
  }

  // ---- epilogue: float4 stores, lin terms fused
  const int rgr = kq * 4;
  float* OutZ = Out + (size_t)z * 8388608;
  const float* lS = linSall + (size_t)z * 8192;
  const float* lE = linEall + (size_t)z * 8192;
#pragma unroll
  for (int mf = 0; mf < 8; ++mf) {
#pragma unroll
    for (int nf = 0; nf < 4; ++nf) {
      const int mBase = m0 + wr * 128 + mf * 16 + rgr;   // = s*8 + c0
      const int e = n0 + wc * 64 + (nf >> 1) * 32 + (nf & 1) * 16 + rA;
      const int s = mBase >> 3;
      const int c0 = mBase & 7;
      const float4 ls4 = *reinterpret_cast<const float4*>(lS + mBase);
      const float4 le4 = *reinterpret_cast<const float4*>(lE + (e << 3) + c0);
      float4 o;
      o.x = acc[mf][nf][0] + ls4.x + le4.x;
      o.y = acc[mf][nf][1] + ls4.y + le4.y;
      o.z = acc[mf][nf][2] + ls4.z + le4.z;
      o.w = acc[mf][nf][3] + ls4.w + le4.w;
      *reinterpret_cast<float4*>(OutZ + ((size_t)s << 13) + ((size_t)e << 3) + c0) = o;
    }
  }
}

// ---------------------------------------------------------------------------
// 2-phase 128-wide B^T GEMM (proven R2 structure) for K1/K2.
// EPI: 0 = bf16 out; 1 = bf16 out + dual bias (n<256 ? b0[n] : b1[n-256])
// ---------------------------------------------------------------------------
template <int IM, int EPI>
__global__ __launch_bounds__(BDIM, 2)
void gemm_bt(const u16* __restrict__ Aall,
             const u16* __restrict__ Ball,
             void* __restrict__ OutAll,
             const int N, const int K, const int lda, const int ldb,
             const float* __restrict__ bias0,
             const float* __restrict__ bias1)
{
  constexpr int WM = IM * 16;
  constexpr int TM = 2 * WM;

  __shared__ u16 lsA[TM * 32];
  __shared__ u16 lsB[128 * 32];

  const int tid  = threadIdx.x;
  const int lane = tid & 63;
  const int wv   = tid >> 6;
  const int wr   = wv >> 1;
  const int wc   = wv & 1;

  const int gx = gridDim.x;
  const int nwg = gx * gridDim.y;
  int id = blockIdx.y * gx + blockIdx.x;
  {
    const int q = nwg >> 3;
    id = (id & 7) * q + (id >> 3);
  }
  const int n0 = (id % gx) * 128;
  const int m0 = (id / gx) * TM;

  const u16* A  = Aall;
  const u16* Bm = Ball;

  f32x4 acc[IM][4];
#pragma unroll
  for (int i = 0; i < IM; ++i)
#pragma unroll
    for (int j = 0; j < 4; ++j) acc[i][j] = (f32x4)0.f;

  const int rA = lane & 15;
  const int ko = (lane >> 4) * 8;

  for (int kt = 0; kt < K; kt += 32) {
    constexpr int CA = TM * 4;
#pragma unroll
    for (int it = 0; it < CA / BDIM; ++it) {
      const int chunk = it * BDIM + tid;
      const int row = chunk >> 2;
      const int ce = (chunk & 3) * 8;
      load_lds16(A + (size_t)(m0 + row) * lda + (kt + ce), &lsA[chunk * 8]);
    }
#pragma unroll
    for (int it = 0; it < 2; ++it) {
      const int chunk = it * BDIM + tid;
      const int row = chunk >> 2;
      const int ce = (chunk & 3) * 8;
      load_lds16(Bm + (size_t)(n0 + row) * ldb + (kt + ce), &lsB[chunk * 8]);
    }
    __syncthreads();

    bf16x8 aF[IM], bF[4];
#pragma unroll
    for (int i = 0; i < IM; ++i)
      aF[i] = *reinterpret_cast<const bf16x8*>(&lsA[(wr * WM + i * 16 + rA) * 32 + ko]);
#pragma unroll
    for (int j = 0; j < 4; ++j)
      bF[j] = *reinterpret_cast<const bf16x8*>(&lsB[(wc * 64 + j * 16 + rA) * 32 + ko]);
#pragma unroll
    for (int i = 0; i < IM; ++i)
#pragma unroll
      for (int j = 0; j < 4; ++j)
        acc[i][j] = __builtin_amdgcn_mfma_f32_16x16x32_bf16(aF[i], bF[j], acc[i][j], 0, 0, 0);
    __syncthreads();
  }

  const int rgr = (lane >> 4) * 4;
  u16* Out = (u16*)OutAll;
#pragma unroll
  for (int i = 0; i < IM; ++i) {
#pragma unroll
    for (int j = 0; j < 4; ++j) {
      const int mBase = m0 + wr * WM + i * 16 + rgr;
      const int n = n0 + wc * 64 + j * 16 + rA;
      float bn = 0.f;
      if constexpr (EPI == 1) bn = (n < 256) ? bias0[n] : bias1[n - 256];
#pragma unroll
      for (int r = 0; r < 4; ++r) {
        Out[(size_t)(mBase + r) * N + n] = f32_to_bf16(acc[i][j][r] + bn);
      }
    }
  }
}

// ---------------------------------------------------------------------------
__global__ void prep_kernel(const float* __restrict__ seq,
                            const float* __restrict__ sw,
                            const float* __restrict__ ew,
                            const float* __restrict__ U,
                            u16* __restrict__ Xbf,
                            u16* __restrict__ wbf,
                            u16* __restrict__ Ut)
{
  const int bid = blockIdx.x;
  const int tid = threadIdx.x;
  if (bid < 4096) {
    const int i = bid * 1024 + tid * 4;
    const float4 v = *reinterpret_cast<const float4*>(seq + i);
    ushort4 o;
    o.x = f32_to_bf16(v.x); o.y = f32_to_bf16(v.y);
    o.z = f32_to_bf16(v.z); o.w = f32_to_bf16(v.w);
    *reinterpret_cast<ushort4*>(Xbf + i) = o;
  } else if (bid < 4608) {
    const int i = (bid - 4096) * 1024 + tid * 4;
    const float* src = (i < 262144) ? (sw + i) : (ew + (i - 262144));
    const float4 v = *reinterpret_cast<const float4*>(src);
    ushort4 o;
    o.x = f32_to_bf16(v.x); o.y = f32_to_bf16(v.y);
    o.z = f32_to_bf16(v.z); o.w = f32_to_bf16(v.w);
    *reinterpret_cast<ushort4*>(wbf + i) = o;
  } else {
    const int i = (bid - 4608) * 1024 + tid * 4;  // i = n*256 + h
    const int n = i >> 8;
    const int h = i & 255;
    ushort4 o;
    o.x = f32_to_bf16(U[(size_t)(h + 0) * 2048 + n]);
    o.y = f32_to_bf16(U[(size_t)(h + 1) * 2048 + n]);
    o.z = f32_to_bf16(U[(size_t)(h + 2) * 2048 + n]);
    o.w = f32_to_bf16(U[(size_t)(h + 3) * 2048 + n]);
    *reinterpret_cast<ushort4*>(Ut + i) = o;
  }
}

__global__ void lin_kernel(const u16* __restrict__ Hboth,
                           const float* __restrict__ Ww,
                           const float* __restrict__ Wb,
                           float* __restrict__ linS,
                           float* __restrict__ linE)
{
  const int idx = blockIdx.x * BDIM + threadIdx.x;
  if (idx >= 4096 * 8) return;
  const int m = idx >> 3;
  const int c = idx & 7;
  const uint4* hs4 = reinterpret_cast<const uint4*>(Hboth + (size_t)m * 512);
  const uint4* he4 = reinterpret_cast<const uint4*>(Hboth + (size_t)m * 512 + 256);
  const float* ws = Ww + c * 512;
  const float* we = ws + 256;
  float s1 = 0.f, s2 = 0.f;
#pragma unroll 4
  for (int t = 0; t < 32; ++t) {
    const uint4 a = hs4[t];
    const uint4 b = he4[t];
    const u32 aw[4] = {a.x, a.y, a.z, a.w};
    const u32 bw[4] = {b.x, b.y, b.z, b.w};
#pragma unroll
    for (int q = 0; q < 4; ++q) {
      const int h = t * 8 + q * 2;
      s1 += bf16lo_to_f32(aw[q]) * ws[h] + bf16hi_to_f32(aw[q]) * ws[h + 1];
      s2 += bf16lo_to_f32(bw[q]) * we[h] + bf16hi_to_f32(bw[q]) * we[h + 1];
    }
  }
  linS[idx] = s1;
  linE[idx] = s2 + Wb[c];
}

// ---------------------------------------------------------------------------
extern "C" void kernel_launch(void* const* d_in, const int* in_sizes, int n_in,
                              void* d_out, int out_size, void* d_ws, size_t ws_size,
                              hipStream_t stream)
{
  const float* seq = (const float*)d_in[0];
  const float* U   = (const float*)d_in[1];
  const float* Ww  = (const float*)d_in[2];
  const float* Wb  = (const float*)d_in[3];
  const float* sw  = (const float*)d_in[4];
  const float* sb  = (const float*)d_in[5];
  const float* ew  = (const float*)d_in[6];
  const float* eb  = (const float*)d_in[7];
  float* out = (float*)d_out;

  u16* Xbf   = (u16*)d_ws;                 // 4194304
  u16* wbf   = Xbf  + 4194304;             // 524288  [512][1024]
  u16* Utbf  = wbf  + 524288;              // 524288  [2048][256]
  u16* Hboth = Utbf + 524288;              // 2097152 [4096][512]
  u16* Tbf   = Hboth + 2097152;            // 8388608 [4096][2048]
  float* linS = (float*)(Tbf + 8388608);   // 32768
  float* linE = linS + 32768;              // 32768

  prep_kernel<<<5120, BDIM, 0, stream>>>(seq, sw, ew, U, Xbf, wbf, Utbf);

  // K1: Hboth = X @ [sw;ew]^T + [sb;eb]  (M=4096, N=512, K=1024)
  gemm_bt<2, 1><<<dim3(4, 64, 1), BDIM, 0, stream>>>(
      Xbf, wbf, Hboth, 512, 1024, 1024, 1024, sb, eb);

  lin_kernel<<<128, BDIM, 0, stream>>>(Hboth, Ww, Wb, linS, linE);

  // K2: T = Hs @ Ut^T   (M=4096, N=2048, K=256)
  gemm_bt<4, 0><<<dim3(16, 32, 1), BDIM, 0, stream>>>(
      Hboth, Utbf, Tbf, 2048, 256, 512, 256, nullptr, nullptr);

  // K3: out[b] = T[b] @ He[b]^T + lin   (256^2 tile, 8-phase)
  hipFuncSetAttribute(reinterpret_cast<const void*>(&gemm256_biaff),
                      hipFuncAttributeMaxDynamicSharedMemorySize, 131072);
  gemm256_biaff<<<dim3(4, 32, 4), 512, 131072, stream>>>(
      Tbf, Hboth + 256, out, linS, linE);
}